// Round 1
// baseline (77.158 us; speedup 1.0000x reference)
//
#include <hip/hip_runtime.h>
#include <hip/hip_bf16.h>

// GaussianVoxelizer: B=1, G=128 gaussians, F=16 features, N=80000 voxels.
// Reference scan's incremental mean == arithmetic mean of masked contributions,
// so we compute sum & count per voxel and divide once.
//
// Inputs (setup_inputs order):
//   d_in[0] grid_coords (N,3) f32
//   d_in[1] means3d     (1,G,3) f32
//   d_in[2] opacities   (1,G,1) f32
//   d_in[3] features    (1,G,F) f32
//   d_in[4] covariances (1,G,3,3) f32
// Output: dens (N) f32 followed by feats (N,F) f32, concatenated flat.

#define GV_GMAX 128
#define GV_F 16

__global__ __launch_bounds__(256)
void GaussianVoxelizer_40467181863368_kernel(
    const float* __restrict__ grid,   // (N,3)
    const float* __restrict__ means,  // (G,3)
    const float* __restrict__ opac,   // (G)
    const float* __restrict__ feats,  // (G,F)
    const float* __restrict__ covs,   // (G,9)
    float* __restrict__ out_dens,     // (N)
    float* __restrict__ out_feat,     // (N,F)
    int N, int G)
{
    __shared__ float s_mean[GV_GMAX][3];
    __shared__ float s_op[GV_GMAX];
    __shared__ float s_inv[GV_GMAX][6];   // symmetric inverse: i00,i01,i02,i11,i12,i22
    __shared__ float s_feat[GV_GMAX][GV_F];

    const int t = threadIdx.x;

    // ---- Stage gaussian params + compute 3x3 symmetric inverse (adjugate) ----
    for (int g = t; g < G; g += blockDim.x) {
        const float c00 = covs[g * 9 + 0];
        const float c01 = covs[g * 9 + 1];
        const float c02 = covs[g * 9 + 2];
        const float c11 = covs[g * 9 + 4];
        const float c12 = covs[g * 9 + 5];
        const float c22 = covs[g * 9 + 8];
        // cofactors (cov is symmetric SPD: cov = A*A^T + 0.1*I, det >= 1e-3)
        const float m00 = c11 * c22 - c12 * c12;
        const float m01 = c02 * c12 - c01 * c22;
        const float m02 = c01 * c12 - c02 * c11;
        const float det = c00 * m00 + c01 * m01 + c02 * m02;
        const float rdet = 1.0f / det;
        s_inv[g][0] = m00 * rdet;
        s_inv[g][1] = m01 * rdet;
        s_inv[g][2] = m02 * rdet;
        s_inv[g][3] = (c00 * c22 - c02 * c02) * rdet;
        s_inv[g][4] = (c01 * c02 - c00 * c12) * rdet;
        s_inv[g][5] = (c00 * c11 - c01 * c01) * rdet;

        s_mean[g][0] = means[g * 3 + 0];
        s_mean[g][1] = means[g * 3 + 1];
        s_mean[g][2] = means[g * 3 + 2];
        s_op[g] = opac[g];
        #pragma unroll
        for (int f = 0; f < GV_F; ++f) s_feat[g][f] = feats[g * GV_F + f];
    }
    __syncthreads();

    const int n = blockIdx.x * blockDim.x + t;
    if (n >= N) return;

    const float px = grid[n * 3 + 0];
    const float py = grid[n * 3 + 1];
    const float pz = grid[n * 3 + 2];

    float cnt = 0.0f;
    float sum_d = 0.0f;
    float sum_f[GV_F];
    #pragma unroll
    for (int f = 0; f < GV_F; ++f) sum_f[f] = 0.0f;

    for (int g = 0; g < G; ++g) {
        const float dx = px - s_mean[g][0];
        const float dy = py - s_mean[g][1];
        const float dz = pz - s_mean[g][2];
        const float maha =
            s_inv[g][0] * dx * dx + s_inv[g][3] * dy * dy + s_inv[g][5] * dz * dz +
            2.0f * (s_inv[g][1] * dx * dy + s_inv[g][2] * dx * dz + s_inv[g][4] * dy * dz);
        if (maha <= 4.0f) {
            const float w = __expf(-0.5f * maha) * s_op[g];
            cnt += 1.0f;
            sum_d += w;
            #pragma unroll
            for (int f = 0; f < GV_F; ++f) sum_f[f] += w * s_feat[g][f];
        }
    }

    const float inv_c = (cnt > 0.0f) ? (1.0f / cnt) : 0.0f;
    out_dens[n] = sum_d * inv_c;

    // 16 contiguous floats per voxel -> 4x float4 stores
    float4* fo = (float4*)(out_feat + (size_t)n * GV_F);
    #pragma unroll
    for (int q = 0; q < 4; ++q) {
        fo[q] = make_float4(sum_f[4 * q + 0] * inv_c,
                            sum_f[4 * q + 1] * inv_c,
                            sum_f[4 * q + 2] * inv_c,
                            sum_f[4 * q + 3] * inv_c);
    }
}

extern "C" void kernel_launch(void* const* d_in, const int* in_sizes, int n_in,
                              void* d_out, int out_size, void* d_ws, size_t ws_size,
                              hipStream_t stream) {
    const float* grid  = (const float*)d_in[0];
    const float* means = (const float*)d_in[1];
    const float* opac  = (const float*)d_in[2];
    const float* feats = (const float*)d_in[3];
    const float* covs  = (const float*)d_in[4];

    const int N = in_sizes[0] / 3;       // 80000
    const int G = in_sizes[2];           // B*G = 128 (B=1)

    float* out_dens = (float*)d_out;         // (N)
    float* out_feat = (float*)d_out + N;     // (N,F)

    const int block = 256;
    const int grid_n = (N + block - 1) / block;
    GaussianVoxelizer_40467181863368_kernel<<<grid_n, block, 0, stream>>>(
        grid, means, opac, feats, covs, out_dens, out_feat, N, G);
}

// Round 2
// 71.441 us; speedup vs baseline: 1.0800x; 1.0800x over previous
//
#include <hip/hip_runtime.h>
#include <hip/hip_bf16.h>

// GaussianVoxelizer: B=1, G=128 gaussians, F=16 features, N=80000 voxels.
// Sum/count formulation (== reference's incremental masked mean).
//
// R2 design: latency-bound fix. 1250 blocks x 256 threads; each block owns 64
// voxels; each of the 4 waves processes a 32-gaussian chunk; partials reduced
// via LDS. 5000 waves (~4.9/SIMD) vs R1's 1250 (~1.2/SIMD).
//
// Inputs (setup_inputs order):
//   d_in[0] grid_coords (N,3) f32
//   d_in[1] means3d     (1,G,3) f32
//   d_in[2] opacities   (1,G,1) f32
//   d_in[3] features    (1,G,F) f32
//   d_in[4] covariances (1,G,3,3) f32
// Output: dens (N) f32 followed by feats (N,F) f32, concatenated flat.

#define GV_GMAX 128
#define GV_F 16
#define GV_NV 64   // voxels per block
#define GV_NW 4    // waves per block
#define GV_RW (GV_F + 2)  // per-voxel partial: cnt, dens, 16 feats

__global__ __launch_bounds__(256)
void GaussianVoxelizer_40467181863368_kernel(
    const float* __restrict__ grid,   // (N,3)
    const float* __restrict__ means,  // (G,3)
    const float* __restrict__ opac,   // (G)
    const float* __restrict__ feats,  // (G,F)
    const float* __restrict__ covs,   // (G,9)
    float* __restrict__ out_dens,     // (N)
    float* __restrict__ out_feat,     // (N,F)
    int N, int G)
{
    __shared__ float s_mean[GV_GMAX][3];
    __shared__ float s_op[GV_GMAX];
    __shared__ float s_inv[GV_GMAX][6];   // i00,i01,i02,i11,i12,i22
    __shared__ float s_feat[GV_GMAX][GV_F];
    __shared__ float s_red[GV_NW][GV_NV][GV_RW];

    const int t = threadIdx.x;

    // ---- Stage gaussian params + symmetric 3x3 inverse (adjugate) ----
    for (int g = t; g < G; g += blockDim.x) {
        const float c00 = covs[g * 9 + 0];
        const float c01 = covs[g * 9 + 1];
        const float c02 = covs[g * 9 + 2];
        const float c11 = covs[g * 9 + 4];
        const float c12 = covs[g * 9 + 5];
        const float c22 = covs[g * 9 + 8];
        const float m00 = c11 * c22 - c12 * c12;
        const float m01 = c02 * c12 - c01 * c22;
        const float m02 = c01 * c12 - c02 * c11;
        const float det = c00 * m00 + c01 * m01 + c02 * m02;
        const float rdet = 1.0f / det;    // cov = A*A^T + 0.1I is SPD, det>=1e-3
        s_inv[g][0] = m00 * rdet;
        s_inv[g][1] = m01 * rdet;
        s_inv[g][2] = m02 * rdet;
        s_inv[g][3] = (c00 * c22 - c02 * c02) * rdet;
        s_inv[g][4] = (c01 * c02 - c00 * c12) * rdet;
        s_inv[g][5] = (c00 * c11 - c01 * c01) * rdet;

        s_mean[g][0] = means[g * 3 + 0];
        s_mean[g][1] = means[g * 3 + 1];
        s_mean[g][2] = means[g * 3 + 2];
        s_op[g] = opac[g];
        #pragma unroll
        for (int f = 0; f < GV_F; ++f) s_feat[g][f] = feats[g * GV_F + f];
    }
    __syncthreads();

    const int wave = t >> 6;
    const int lane = t & 63;
    const int n = blockIdx.x * GV_NV + lane;

    float px = 0.0f, py = 0.0f, pz = 0.0f;
    if (n < N) {
        px = grid[n * 3 + 0];
        py = grid[n * 3 + 1];
        pz = grid[n * 3 + 2];
    }

    const int chunk = (G + GV_NW - 1) / GV_NW;
    const int g0 = wave * chunk;
    const int g1 = (g0 + chunk < G) ? (g0 + chunk) : G;

    float cnt = 0.0f;
    float sum_d = 0.0f;
    float sum_f[GV_F];
    #pragma unroll
    for (int f = 0; f < GV_F; ++f) sum_f[f] = 0.0f;

    if (n < N) {
        #pragma unroll 4
        for (int g = g0; g < g1; ++g) {
            const float dx = px - s_mean[g][0];
            const float dy = py - s_mean[g][1];
            const float dz = pz - s_mean[g][2];
            const float maha =
                s_inv[g][0] * dx * dx + s_inv[g][3] * dy * dy + s_inv[g][5] * dz * dz +
                2.0f * (s_inv[g][1] * dx * dy + s_inv[g][2] * dx * dz + s_inv[g][4] * dy * dz);
            if (maha <= 4.0f) {
                const float w = __expf(-0.5f * maha) * s_op[g];
                cnt += 1.0f;
                sum_d += w;
                #pragma unroll
                for (int f = 0; f < GV_F; ++f) sum_f[f] += w * s_feat[g][f];
            }
        }
    }

    // ---- Write per-wave partials to LDS ----
    {
        float* r = &s_red[wave][lane][0];
        r[0] = cnt;
        r[1] = sum_d;
        #pragma unroll
        for (int f = 0; f < GV_F; ++f) r[2 + f] = sum_f[f];
    }
    __syncthreads();

    // ---- Reduce across the 4 waves; threads 0..63 finalize one voxel each ----
    if (t < GV_NV) {
        const int n2 = blockIdx.x * GV_NV + t;
        if (n2 < N) {
            float c = 0.0f, d = 0.0f;
            float ff[GV_F];
            #pragma unroll
            for (int f = 0; f < GV_F; ++f) ff[f] = 0.0f;
            #pragma unroll
            for (int w = 0; w < GV_NW; ++w) {
                const float* r = &s_red[w][t][0];
                c += r[0];
                d += r[1];
                #pragma unroll
                for (int f = 0; f < GV_F; ++f) ff[f] += r[2 + f];
            }
            const float inv_c = (c > 0.0f) ? (1.0f / c) : 0.0f;
            out_dens[n2] = d * inv_c;
            float4* fo = (float4*)(out_feat + (size_t)n2 * GV_F);
            #pragma unroll
            for (int q = 0; q < 4; ++q) {
                fo[q] = make_float4(ff[4 * q + 0] * inv_c,
                                    ff[4 * q + 1] * inv_c,
                                    ff[4 * q + 2] * inv_c,
                                    ff[4 * q + 3] * inv_c);
            }
        }
    }
}

extern "C" void kernel_launch(void* const* d_in, const int* in_sizes, int n_in,
                              void* d_out, int out_size, void* d_ws, size_t ws_size,
                              hipStream_t stream) {
    const float* grid  = (const float*)d_in[0];
    const float* means = (const float*)d_in[1];
    const float* opac  = (const float*)d_in[2];
    const float* feats = (const float*)d_in[3];
    const float* covs  = (const float*)d_in[4];

    const int N = in_sizes[0] / 3;       // 80000
    const int G = in_sizes[2];           // B*G = 128 (B=1)

    float* out_dens = (float*)d_out;         // (N)
    float* out_feat = (float*)d_out + N;     // (N,F)

    const int block = 256;
    const int grid_n = (N + GV_NV - 1) / GV_NV;   // 1250 blocks
    GaussianVoxelizer_40467181863368_kernel<<<grid_n, block, 0, stream>>>(
        grid, means, opac, feats, covs, out_dens, out_feat, N, G);
}